// Round 9
// baseline (445.884 us; speedup 1.0000x reference)
//
#include <hip/hip_runtime.h>
#include <cstdint>
#include <cstddef>

#define NN 50000
#define NE 200000
#define IND 768
#define HID 256
#define OUTD 64
#define NB 196    // ceil(NN/256)
#define NEB 782   // ceil(NE/256) edge-prep blocks
#define NWB 1024  // weights blocks (4 x 256 linearized)
#define NCB 2048  // grid-stride cast blocks (persistent waves, ~9 iters/thread)

typedef __bf16 bf16;
typedef __bf16 bf16x8 __attribute__((ext_vector_type(8)));
typedef __bf16 bf16x4 __attribute__((ext_vector_type(4)));
typedef float f32x4 __attribute__((ext_vector_type(4)));

// ---------------- front: EDGE first, weights (+eW) second, cast last ----------
// r8 postmortem: the 400k contended scatter-atomics (782 blocks) were LAST in the
// grid; the 2048 cast blocks fill all 256 CUs (8 blocks/CU) for their whole
// duration, so the atomics drained on an emptying machine (~50 us tail;
// occupancy 58%). Ordering edge-prep FIRST overlaps the latency-bound atomic
// drain with the BW-bound cast stream. eW keeps the r8 4-accumulator unroll.
__global__ __launch_bounds__(256) void k_front(const int* __restrict__ ei,
                                               int* __restrict__ le, int* __restrict__ deg,
                                               const float* __restrict__ x,
                                               bf16* __restrict__ A1,
                                               const float* __restrict__ W1,
                                               const float* __restrict__ W2,
                                               const float* __restrict__ eemb,
                                               bf16* __restrict__ W1t,
                                               bf16* __restrict__ W2t,
                                               float* __restrict__ eW) {
  const int bid = blockIdx.x, tid = threadIdx.x;
  if (bid < NEB) {
    int e = bid * 256 + tid;
    if (e < NE) {
      atomicMax(&le[ei[e]], e);        // src: last edge index wins
      atomicAdd(&deg[ei[NE + e]], 1);  // dst degree
    }
  } else if (bid < NEB + NWB) {
    int wb = bid - NEB, bx = wb >> 8, by = wb & 255;
    if (bx < 3) {
      int k = bx * 256 + tid;
      W1t[by * IND + k] = (bf16)W1[(size_t)k * HID + by];
    } else if (by < OUTD) {
      W2t[by * HID + tid] = (bf16)W2[(size_t)tid * OUTD + by];
    } else if (by < OUTD + 7) {
      int r = by - OUTD;
      float s0 = 0.f, s1 = 0.f, s2 = 0.f, s3 = 0.f;
      if (r < 6) {
        const float* er = eemb + (size_t)r * IND;
#pragma unroll 4
        for (int k = 0; k < IND; k += 4) {
          s0 += er[k]     * W1[(size_t)k * HID + tid];
          s1 += er[k + 1] * W1[(size_t)(k + 1) * HID + tid];
          s2 += er[k + 2] * W1[(size_t)(k + 2) * HID + tid];
          s3 += er[k + 3] * W1[(size_t)(k + 3) * HID + tid];
        }
      }
      eW[r * HID + tid] = (s0 + s1) + (s2 + s3);  // row 6 = zeros ("no edge")
    }
  } else {
    const size_t total = (size_t)NN * IND / 8;  // 8 elems per thread-iteration
    const int cb = bid - NEB - NWB;
    for (size_t idx = (size_t)cb * 256 + tid; idx < total; idx += (size_t)NCB * 256) {
      const float* px = x + idx * 8;
      float4 v0 = *(const float4*)px, v1 = *(const float4*)(px + 4);
      bf16x8 o;
      o[0] = (bf16)v0.x; o[1] = (bf16)v0.y; o[2] = (bf16)v0.z; o[3] = (bf16)v0.w;
      o[4] = (bf16)v1.x; o[5] = (bf16)v1.y; o[6] = (bf16)v1.z; o[7] = (bf16)v1.w;
      *(bf16x8*)(A1 + idx * 8) = o;
    }
  }
}

// ---------------- CSR build: scan + scatter ----------------
__global__ __launch_bounds__(256) void k_scan_block(const int* __restrict__ deg,
                                                    int* __restrict__ excl, int* __restrict__ bsum) {
  __shared__ int sm[256];
  int tid = threadIdx.x;
  int i = blockIdx.x * 256 + tid;
  int v = (i < NN) ? deg[i] : 0;
  sm[tid] = v;
  __syncthreads();
#pragma unroll
  for (int off = 1; off < 256; off <<= 1) {
    int t = (tid >= off) ? sm[tid - off] : 0;
    __syncthreads();
    sm[tid] += t;
    __syncthreads();
  }
  if (i < NN) excl[i] = sm[tid] - v;
  if (tid == 255) bsum[blockIdx.x] = sm[255];
}

__global__ __launch_bounds__(256) void k_scan_partials(const int* __restrict__ bsum,
                                                       int* __restrict__ bbase) {
  __shared__ int sm[256];
  int tid = threadIdx.x;
  int v = (tid < NB) ? bsum[tid] : 0;
  sm[tid] = v;
  __syncthreads();
#pragma unroll
  for (int off = 1; off < 256; off <<= 1) {
    int t = (tid >= off) ? sm[tid - off] : 0;
    __syncthreads();
    sm[tid] += t;
    __syncthreads();
  }
  bbase[tid] = sm[tid] - v;
}

// also derives eidx[i] = edge-type row for node i (6 = none) for the GEMM1 epilogue
__global__ __launch_bounds__(256) void k_add_base(const int* __restrict__ excl,
                                                  const int* __restrict__ bbase,
                                                  int* __restrict__ rowstart, int* __restrict__ cur,
                                                  const int* __restrict__ le,
                                                  const int* __restrict__ et,
                                                  int* __restrict__ eidx) {
  int i = blockIdx.x * 256 + threadIdx.x;
  if (i < NN) {
    int rs = excl[i] + bbase[i >> 8];
    rowstart[i] = rs;
    cur[i] = rs;
    int l = le[i];
    eidx[i] = (l >= 0) ? et[l] : 6;
  }
}

__global__ __launch_bounds__(256) void k_scatter_csr(const int* __restrict__ ei,
                                                     int* __restrict__ cur, int* __restrict__ csr) {
  int e = blockIdx.x * 256 + threadIdx.x;
  if (e < NE) {
    int d = ei[NE + e];
    int pos = atomicAdd(&cur[d], 1);
    csr[pos] = ei[e];  // store src node id
  }
}

__device__ __forceinline__ void gld16(const bf16* g, bf16* l) {
  __builtin_amdgcn_global_load_lds((const __attribute__((address_space(1))) void*)g,
                                   (__attribute__((address_space(3))) void*)l, 16, 0, 0);
}

// ---------------- GEMM1: h1[M,256] = A1[M,768] * W1t[256,768]^T, single col-pass ----------
// 128x256 tile, 8 waves (2x4), 512 threads, BK=32. A1 read ONCE (r8: grid.x=2
// fetched every A row twice -> FETCH 76MB; now ~45MB). Same verified pipeline:
// triple-buffer, distance-2, one barrier/K-step, counted vmcnt (3 gld16/wave/
// stage -> vmcnt(3) steady, 0 only at tail). Epilogue adds eW[eidx[row]]
// (linearity fold) and emits per-head attention logits.
__global__ __launch_bounds__(512) void k_gemm1(const bf16* __restrict__ A,
                                               const bf16* __restrict__ Bt,
                                               bf16* __restrict__ C,
                                               const float* __restrict__ aS,
                                               const float* __restrict__ aD,
                                               float* __restrict__ alS,
                                               float* __restrict__ alD,
                                               const int* __restrict__ eidx,
                                               const float* __restrict__ eW) {
  const int M = NN, K = IND;
  __shared__ bf16 As[3][128 * 32];
  __shared__ bf16 Bs[3][256 * 32];
  const int tid = threadIdx.x;
  const int lane = tid & 63;
  const int wave = tid >> 6;        // 0..7
  const int wr = wave >> 2;         // 0..1 (64-row slice)
  const int wc = wave & 3;          // 0..3 (64-col slice = head)
  const int ln15 = lane & 15, q = lane >> 4;
  const int m0 = blockIdx.x * 128;

  // staging: wave stages 16 A rows (1 call) + 32 B rows (2 calls) per tile.
  const int sr = lane >> 2;
  const int scol = (lane & 3) * 8;
  const int gA0 = min(m0 + wave * 16 + sr, M - 1);
  const int gB0 = wave * 32 + sr;        // [0,256)
  const int gB1 = wave * 32 + 16 + sr;

  auto stage = [&](int buf, int kt) {
    gld16(A + (size_t)gA0 * K + kt + scol, &As[buf][(wave * 16) * 32]);
    gld16(Bt + (size_t)gB0 * K + kt + scol, &Bs[buf][(wave * 32) * 32]);
    gld16(Bt + (size_t)gB1 * K + kt + scol, &Bs[buf][(wave * 32 + 16) * 32]);
  };

  f32x4 acc[4][4] = {};

  auto compute = [&](int buf) {
    bf16x8 af[4], bfr[4];
#pragma unroll
    for (int i = 0; i < 4; i++)
      af[i] = *(const bf16x8*)(&As[buf][(wr * 64 + i * 16 + ln15) * 32 + q * 8]);
#pragma unroll
    for (int i = 0; i < 4; i++)
      bfr[i] = *(const bf16x8*)(&Bs[buf][(wc * 64 + i * 16 + ln15) * 32 + q * 8]);
#pragma unroll
    for (int mi = 0; mi < 4; mi++)
#pragma unroll
      for (int ni = 0; ni < 4; ni++)
        acc[mi][ni] = __builtin_amdgcn_mfma_f32_16x16x32_bf16(af[mi], bfr[ni], acc[mi][ni], 0, 0, 0);
  };

  const int NT = K >> 5;  // 24

  stage(0, 0);
  stage(1, 32);
  for (int t = 0; t < NT; ++t) {
    if (t + 2 < NT) asm volatile("s_waitcnt vmcnt(3)" ::: "memory");
    else            asm volatile("s_waitcnt vmcnt(0)" ::: "memory");
    __builtin_amdgcn_sched_barrier(0);
    __builtin_amdgcn_s_barrier();  // publish tile t
    if (t + 2 < NT) stage((t + 2) % 3, (t + 2) << 5);
    compute(t % 3);
    asm volatile("s_waitcnt lgkmcnt(0)" ::: "memory");  // my reads of tile t done
    __builtin_amdgcn_sched_barrier(0);
  }

  // epilogue 0: acc += eW[eidx[row]][col]
#pragma unroll
  for (int mi = 0; mi < 4; mi++)
#pragma unroll
    for (int r = 0; r < 4; r++) {
      int row = m0 + wr * 64 + mi * 16 + q * 4 + r;
      int e = eidx[min(row, M - 1)];
      const float* ew = eW + e * HID + wc * 64 + ln15;
#pragma unroll
      for (int ni = 0; ni < 4; ni++) acc[mi][ni][r] += ew[ni * 16];
    }

  // epilogue 1: C store (C/D layout col=lane&15, row=(lane>>4)*4+reg)
#pragma unroll
  for (int mi = 0; mi < 4; mi++)
#pragma unroll
    for (int ni = 0; ni < 4; ni++)
#pragma unroll
      for (int r = 0; r < 4; r++) {
        int row = m0 + wr * 64 + mi * 16 + q * 4 + r;
        int col = wc * 64 + ni * 16 + ln15;
        if (row < M) C[(size_t)row * HID + col] = (bf16)acc[mi][ni][r];
      }

  // epilogue 2: attention logits (head hd == wc; one wave per (row,hd))
  {
    const int hd = wc;
#pragma unroll
    for (int mi = 0; mi < 4; mi++)
#pragma unroll
      for (int r = 0; r < 4; r++) {
        float ps = 0.f, pd = 0.f;
#pragma unroll
        for (int ni = 0; ni < 4; ni++) {
          int col = wc * 64 + ni * 16 + ln15;
          ps += acc[mi][ni][r] * aS[col];
          pd += acc[mi][ni][r] * aD[col];
        }
#pragma unroll
        for (int off = 1; off < 16; off <<= 1) {
          ps += __shfl_xor(ps, off);
          pd += __shfl_xor(pd, off);
        }
        int row = m0 + wr * 64 + mi * 16 + q * 4 + r;
        if (ln15 == 0 && row < M) {
          alS[row * 4 + hd] = ps;
          alD[row * 4 + hd] = pd;
        }
      }
  }
}

// ---------------- GEMM2: C[M,64] = A[M,256] * Bt[64,256]^T (TN=64, 4 waves) ----------
// Same verified triple-buffer pipeline; 4x1 waves, 2x4 frags/wave.
__global__ __launch_bounds__(256) void k_gemm2(const bf16* __restrict__ A,
                                               const bf16* __restrict__ Bt,
                                               float* __restrict__ C,
                                               const float* __restrict__ aS,
                                               const float* __restrict__ aD,
                                               float* __restrict__ alS,
                                               float* __restrict__ alD) {
  const int M = NN, K = HID, NC = OUTD;
  __shared__ bf16 As[3][128 * 32];
  __shared__ bf16 Bs[3][64 * 32];
  const int tid = threadIdx.x;
  const int lane = tid & 63;
  const int wave = tid >> 6;
  const int ln15 = lane & 15, q = lane >> 4;
  const int m0 = blockIdx.x * 128;

  const int sr = lane >> 2;
  const int scol = (lane & 3) * 8;
  const int gA0 = min(m0 + wave * 32 + sr, M - 1);
  const int gA1 = min(m0 + wave * 32 + 16 + sr, M - 1);
  const int gB0 = min(wave * 16 + sr, NC - 1);

  auto stage = [&](int buf, int kt) {
    gld16(A + (size_t)gA0 * K + kt + scol, &As[buf][(wave * 32) * 32]);
    gld16(A + (size_t)gA1 * K + kt + scol, &As[buf][(wave * 32 + 16) * 32]);
    gld16(Bt + (size_t)gB0 * K + kt + scol, &Bs[buf][(wave * 16) * 32]);
  };

  f32x4 acc[2][4] = {};

  auto compute = [&](int buf) {
    bf16x8 af[2], bfr[4];
#pragma unroll
    for (int i = 0; i < 2; i++)
      af[i] = *(const bf16x8*)(&As[buf][(wave * 32 + i * 16 + ln15) * 32 + q * 8]);
#pragma unroll
    for (int i = 0; i < 4; i++)
      bfr[i] = *(const bf16x8*)(&Bs[buf][(i * 16 + ln15) * 32 + q * 8]);
#pragma unroll
    for (int mi = 0; mi < 2; mi++)
#pragma unroll
      for (int ni = 0; ni < 4; ni++)
        acc[mi][ni] = __builtin_amdgcn_mfma_f32_16x16x32_bf16(af[mi], bfr[ni], acc[mi][ni], 0, 0, 0);
  };

  const int NT = K >> 5;  // 8

  stage(0, 0);
  stage(1, 32);
  for (int t = 0; t < NT; ++t) {
    if (t + 2 < NT) asm volatile("s_waitcnt vmcnt(3)" ::: "memory");
    else            asm volatile("s_waitcnt vmcnt(0)" ::: "memory");
    __builtin_amdgcn_sched_barrier(0);
    __builtin_amdgcn_s_barrier();
    if (t + 2 < NT) stage((t + 2) % 3, (t + 2) << 5);
    compute(t % 3);
    asm volatile("s_waitcnt lgkmcnt(0)" ::: "memory");
    __builtin_amdgcn_sched_barrier(0);
  }

#pragma unroll
  for (int mi = 0; mi < 2; mi++)
#pragma unroll
    for (int ni = 0; ni < 4; ni++)
#pragma unroll
      for (int r = 0; r < 4; r++) {
        int row = m0 + wave * 32 + mi * 16 + q * 4 + r;
        int col = ni * 16 + ln15;
        if (row < M) C[(size_t)row * NC + col] = acc[mi][ni][r];
      }

#pragma unroll
  for (int mi = 0; mi < 2; mi++)
#pragma unroll
    for (int r = 0; r < 4; r++) {
      float ps = 0.f, pd = 0.f;
#pragma unroll
      for (int ni = 0; ni < 4; ni++) {
        int col = ni * 16 + ln15;
        ps += acc[mi][ni][r] * aS[col];
        pd += acc[mi][ni][r] * aD[col];
      }
#pragma unroll
      for (int off = 1; off < 16; off <<= 1) {
        ps += __shfl_xor(ps, off);
        pd += __shfl_xor(pd, off);
      }
      int row = m0 + wave * 32 + mi * 16 + q * 4 + r;
      if (ln15 == 0 && row < M) {
        alS[row] = ps;
        alD[row] = pd;
      }
    }
}

// ---------------- fused gather-aggregate + LN + ELU, layer 1 ----------------
__global__ __launch_bounds__(256) void k_agg_ln1(const int* __restrict__ rowstart,
                                                 const int* __restrict__ deg,
                                                 const int* __restrict__ csr,
                                                 const bf16* __restrict__ h1,
                                                 const float* __restrict__ alS,
                                                 const float* __restrict__ alD,
                                                 const float* __restrict__ b1,
                                                 const float* __restrict__ g1,
                                                 const float* __restrict__ be1,
                                                 bf16* __restrict__ hln) {
  const int n = blockIdx.x * 4 + (threadIdx.x >> 6);  // 50000 % 4 == 0
  const int lane = threadIdx.x & 63;
  const int f0 = lane * 4;       // 4 consecutive feats, same head (4 | 64)
  const int hd = lane >> 4;
  int start = rowstart[n], cnt = deg[n];
  float ald = alD[n * 4 + hd];
  float accv0 = 0.f, accv1 = 0.f, accv2 = 0.f, accv3 = 0.f, accw = 0.f;
  for (int j = 0; j < cnt; j++) {
    int s = csr[start + j];
    float logit = alS[s * 4 + hd] + ald;
    logit = logit >= 0.f ? logit : 0.2f * logit;
    float w = __expf(logit);  // shift-free softmax: logits bounded by construction
    bf16x4 hv = *(const bf16x4*)(h1 + (size_t)s * HID + f0);
    accv0 += w * (float)hv[0];
    accv1 += w * (float)hv[1];
    accv2 += w * (float)hv[2];
    accv3 += w * (float)hv[3];
    accw += w;
  }
  float inv = (cnt > 0) ? 1.f / accw : 0.f;
  float4 bv = *(const float4*)(b1 + f0);
  float v0 = accv0 * inv + bv.x;
  float v1 = accv1 * inv + bv.y;
  float v2 = accv2 * inv + bv.z;
  float v3 = accv3 * inv + bv.w;
  float s = v0 + v1 + v2 + v3;
  float ss = v0 * v0 + v1 * v1 + v2 * v2 + v3 * v3;
#pragma unroll
  for (int off = 32; off; off >>= 1) { s += __shfl_xor(s, off); ss += __shfl_xor(ss, off); }
  float mu = s * (1.f / HID);
  float var = ss * (1.f / HID) - mu * mu;
  float rs = rsqrtf(var + 1e-5f);
  float4 gv = *(const float4*)(g1 + f0);
  float4 ev = *(const float4*)(be1 + f0);
  float y0 = (v0 - mu) * rs * gv.x + ev.x;
  float y1 = (v1 - mu) * rs * gv.y + ev.y;
  float y2 = (v2 - mu) * rs * gv.z + ev.z;
  float y3 = (v3 - mu) * rs * gv.w + ev.w;
  y0 = y0 > 0.f ? y0 : __expf(y0) - 1.f;  // ELU
  y1 = y1 > 0.f ? y1 : __expf(y1) - 1.f;
  y2 = y2 > 0.f ? y2 : __expf(y2) - 1.f;
  y3 = y3 > 0.f ? y3 : __expf(y3) - 1.f;
  bf16x4 o;
  o[0] = (bf16)y0; o[1] = (bf16)y1; o[2] = (bf16)y2; o[3] = (bf16)y3;
  *(bf16x4*)(hln + (size_t)n * HID + f0) = o;
}

// ---------------- fused gather-aggregate + LN, layer 2 ----------------
__global__ __launch_bounds__(256) void k_agg_ln2(const int* __restrict__ rowstart,
                                                 const int* __restrict__ deg,
                                                 const int* __restrict__ csr,
                                                 const float* __restrict__ h2,
                                                 const float* __restrict__ alS,
                                                 const float* __restrict__ alD,
                                                 const float* __restrict__ b2,
                                                 const float* __restrict__ g2,
                                                 const float* __restrict__ be2,
                                                 float* __restrict__ out) {
  const int n = blockIdx.x * 4 + (threadIdx.x >> 6);
  const int f = threadIdx.x & 63;
  int start = rowstart[n], cnt = deg[n];
  float ald = alD[n];
  float accv = 0.f, accw = 0.f;
  for (int j = 0; j < cnt; j++) {
    int s = csr[start + j];
    float logit = alS[s] + ald;
    logit = logit >= 0.f ? logit : 0.2f * logit;
    float w = __expf(logit);
    accv += w * h2[(size_t)s * OUTD + f];
    accw += w;
  }
  float v = (cnt > 0) ? accv / accw : 0.f;
  v += b2[f];
  float s = v, ss = v * v;
#pragma unroll
  for (int off = 32; off; off >>= 1) { s += __shfl_xor(s, off); ss += __shfl_xor(ss, off); }
  float mu = s * (1.f / OUTD);
  float var = ss * (1.f / OUTD) - mu * mu;
  out[(size_t)n * OUTD + f] = (v - mu) * rsqrtf(var + 1e-5f) * g2[f] + be2[f];
}

extern "C" void kernel_launch(void* const* d_in, const int* in_sizes, int n_in,
                              void* d_out, int out_size, void* d_ws, size_t ws_size,
                              hipStream_t stream) {
  const float* x    = (const float*)d_in[0];
  const int*   ei   = (const int*)d_in[1];
  const int*   et   = (const int*)d_in[2];
  const float* eemb = (const float*)d_in[3];
  const float* W1   = (const float*)d_in[4];
  const float* as1  = (const float*)d_in[5];
  const float* ad1  = (const float*)d_in[6];
  const float* b1   = (const float*)d_in[7];
  const float* g1   = (const float*)d_in[8];
  const float* be1  = (const float*)d_in[9];
  const float* W2   = (const float*)d_in[10];
  const float* as2  = (const float*)d_in[11];
  const float* ad2  = (const float*)d_in[12];
  const float* b2   = (const float*)d_in[13];
  const float* g2   = (const float*)d_in[14];
  const float* be2  = (const float*)d_in[15];
  float* out = (float*)d_out;

  char* base = (char*)d_ws;
  size_t off = 0;
  auto alloc = [&](size_t bytes) -> void* {
    void* p = base + off;
    off = (off + bytes + 255) & ~(size_t)255;
    return p;
  };
  int*   le    = (int*)alloc((size_t)NN * 4);
  int*   deg   = (int*)alloc((size_t)NN * 4);
  int*   excl  = (int*)alloc((size_t)NN * 4);
  int*   bsum  = (int*)alloc(256 * 4);
  int*   bbase = (int*)alloc(256 * 4);
  int*   rowst = (int*)alloc((size_t)NN * 4);
  int*   cur   = (int*)alloc((size_t)NN * 4);
  int*   eidx  = (int*)alloc((size_t)NN * 4);
  int*   csr   = (int*)alloc((size_t)NE * 4);
  bf16*  h1    = (bf16*)alloc((size_t)NN * HID * 2);
  float* alS1  = (float*)alloc((size_t)NN * 4 * 4);
  float* alD1  = (float*)alloc((size_t)NN * 4 * 4);
  bf16*  W1t   = (bf16*)alloc((size_t)HID * IND * 2);
  bf16*  W2t   = (bf16*)alloc((size_t)OUTD * HID * 2);
  float* eW    = (float*)alloc((size_t)7 * HID * 4);
  // region R: A1 (live front..gemm1) aliased by {hln, h2, alS2, alD2} (live after gemm1)
  char*  R     = (char*)alloc((size_t)NN * IND * 2);
  bf16*  A1    = (bf16*)R;
  bf16*  hln   = (bf16*)R;
  float* h2    = (float*)(R + (size_t)NN * HID * 2);
  float* alS2  = (float*)(R + (size_t)NN * HID * 2 + (size_t)NN * OUTD * 4);
  float* alD2  = (float*)(R + (size_t)NN * HID * 2 + (size_t)NN * OUTD * 4 + (size_t)NN * 4);

  hipMemsetAsync(le, 0xFF, (size_t)NN * 4, stream);  // -1
  hipMemsetAsync(deg, 0, (size_t)NN * 4, stream);

  // one front launch: edge prep (first: atomics overlap cast), weights+eW, cast
  k_front<<<NEB + NWB + NCB, 256, 0, stream>>>(ei, le, deg, x, A1, W1, W2, eemb, W1t, W2t, eW);
  k_scan_block<<<NB, 256, 0, stream>>>(deg, excl, bsum);
  k_scan_partials<<<1, 256, 0, stream>>>(bsum, bbase);
  k_add_base<<<NB, 256, 0, stream>>>(excl, bbase, rowst, cur, le, et, eidx);
  k_scatter_csr<<<NEB, 256, 0, stream>>>(ei, cur, csr);

  // layer 1: single column-pass 128x256 GEMM (A1 read once), eW epilogue fold
  k_gemm1<<<(NN + 127) / 128, 512, 0, stream>>>(A1, W1t, h1, as1, ad1, alS1, alD1, eidx, eW);
  k_agg_ln1<<<NN / 4, 256, 0, stream>>>(rowst, deg, csr, h1, alS1, alD1, b1, g1, be1, hln);

  // layer 2: narrow GEMM (TN=64)
  k_gemm2<<<(NN + 127) / 128, 256, 0, stream>>>(hln, W2t, h2, as2, ad2, alS2, alD2);
  k_agg_ln2<<<NN / 4, 256, 0, stream>>>(rowst, deg, csr, h2, alS2, alD2, b2, g2, be2, out);
}